// Round 1
// baseline (255.142 us; speedup 1.0000x reference)
//
#include <hip/hip_runtime.h>
#include <hip/hip_bf16.h>

#define NPIX 4096   // 64*64 pixels per batch
#define CCH  64     // channels
#define NB   8      // batch

typedef __attribute__((ext_vector_type(8))) short short8;   // 8 bf16 (4 VGPRs) MFMA A/B frag
typedef __attribute__((ext_vector_type(4))) float f32x4;    // MFMA C/D frag

// ---------------------------------------------------------------------------
// Kernel 1: fused 1x1-conv projections.
//   Q[b][i][oc] = (W1 x + b1)[oc][i]   (bf16, pixel-major for QK^T A/B frags)
//   G[b][j][oc] = (W2 x + b2)[oc][j]   (bf16, pixel-major)
//   K[b][oc][j] = (W3 x + b3)[oc][j]   (bf16, channel-major for PV B frags)
// ---------------------------------------------------------------------------
__global__ __launch_bounds__(256) void proj_kernel(
    const float* __restrict__ x,
    const float* __restrict__ W1, const float* __restrict__ b1,
    const float* __restrict__ W2, const float* __restrict__ b2,
    const float* __restrict__ W3, const float* __restrict__ b3,
    __hip_bfloat16* __restrict__ Q, __hip_bfloat16* __restrict__ G,
    __hip_bfloat16* __restrict__ K)
{
    const int b  = blockIdx.x >> 6;          // 64 pixel-tiles per batch
    const int i0 = (blockIdx.x & 63) << 6;   // tile of 64 pixels

    __shared__ float xs[64][65];             // xs[c][p], padded
    __shared__ float Wt[3][64][68];          // Wt[m][c][oc]  (transposed W, rows 16B-aligned)

    for (int e = threadIdx.x; e < 4096; e += 256) {
        const int c = e >> 6, p = e & 63;
        xs[c][p] = x[(size_t)b * CCH * NPIX + (size_t)c * NPIX + i0 + p];
        // coalesced read of W[oc][c] (oc=e>>6, c=e&63), transposed store
        Wt[0][e & 63][e >> 6] = W1[e];
        Wt[1][e & 63][e >> 6] = W2[e];
        Wt[2][e & 63][e >> 6] = W3[e];
    }
    __syncthreads();

    const int p = threadIdx.x & 63;          // pixel within tile
    const int g = threadIdx.x >> 6;          // out-channel block [16g, 16g+16)

    float acc0[16], acc1[16], acc2[16];
    #pragma unroll
    for (int oo = 0; oo < 16; ++oo) {
        acc0[oo] = b1[g * 16 + oo];
        acc1[oo] = b2[g * 16 + oo];
        acc2[oo] = b3[g * 16 + oo];
    }

    for (int c = 0; c < 64; ++c) {
        const float xv = xs[c][p];
        const f32x4* w0 = (const f32x4*)&Wt[0][c][g * 16];
        const f32x4* w1 = (const f32x4*)&Wt[1][c][g * 16];
        const f32x4* w2 = (const f32x4*)&Wt[2][c][g * 16];
        #pragma unroll
        for (int q = 0; q < 4; ++q) {
            const f32x4 a = w0[q], bb = w1[q], cc = w2[q];
            #pragma unroll
            for (int j = 0; j < 4; ++j) {
                acc0[q * 4 + j] += a[j] * xv;
                acc1[q * 4 + j] += bb[j] * xv;
                acc2[q * 4 + j] += cc[j] * xv;
            }
        }
    }

    const int i = i0 + p;
    #pragma unroll
    for (int oo = 0; oo < 16; ++oo) {
        const int oc = g * 16 + oo;
        Q[(size_t)b * NPIX * CCH + (size_t)i * CCH + oc] = __float2bfloat16(acc0[oo]);
        G[(size_t)b * NPIX * CCH + (size_t)i * CCH + oc] = __float2bfloat16(acc1[oo]);
        K[(size_t)b * CCH * NPIX + (size_t)oc * NPIX + i] = __float2bfloat16(acc2[oo]);
    }
}

// ---------------------------------------------------------------------------
// Kernel 2: flash attention.  Per block: batch b, 64 Q-rows (4 waves x 16).
// Wave loop over j-tiles of 64: scores = Q·G^T (mfma 16x16x32 bf16, K=64),
// online softmax (16-lane shfl reductions), P -> LDS -> PV A-frags,
// O += P·K^T. Epilogue: O/lsum + x, transposed through LDS for coalesced out.
// MFMA frag layouts (gfx950 16x16x32 bf16, m91/m97-verified):
//   A: row = lane&15,  k = 8*(lane>>4) + t   (one contiguous 16B load)
//   B: col = lane&15,  k = 8*(lane>>4) + t
//   C/D: col = lane&15, row = (lane>>4)*4 + r
// ---------------------------------------------------------------------------
__global__ __launch_bounds__(256) void attn_kernel(
    const __hip_bfloat16* __restrict__ Qg, const __hip_bfloat16* __restrict__ Gg,
    const __hip_bfloat16* __restrict__ Kg, const float* __restrict__ x,
    float* __restrict__ out)
{
    const int b     = blockIdx.x >> 6;        // 64 i-tiles per batch
    const int itile = blockIdx.x & 63;
    const int wave  = threadIdx.x >> 6;
    const int lane  = threadIdx.x & 63;
    const int l16   = lane & 15;
    const int lg    = lane >> 4;              // 0..3
    const int i0b   = itile * 64;             // block's first row
    const int i0    = i0b + wave * 16;        // wave's first row

    const short* Qb = (const short*)Qg + (size_t)b * NPIX * CCH;
    const short* Gb = (const short*)Gg + (size_t)b * NPIX * CCH;
    const short* Kb = (const short*)Kg + (size_t)b * CCH * NPIX;

    // Q A-frags (held for whole kernel): rows i0..i0+15, k-chunks c and c+32
    const short* qrow = Qb + (size_t)(i0 + l16) * CCH + 8 * lg;
    const short8 qa0 = *(const short8*)(qrow);
    const short8 qa1 = *(const short8*)(qrow + 32);

    f32x4 o[4];
    #pragma unroll
    for (int nc = 0; nc < 4; ++nc) o[nc] = (f32x4){0.f, 0.f, 0.f, 0.f};
    float m[4], lsum[4];
    #pragma unroll
    for (int r = 0; r < 4; ++r) { m[r] = -1e30f; lsum[r] = 0.f; }

    __shared__ __hip_bfloat16 Plds[4][16][72];   // per-wave P tile, rows 16B-aligned

    for (int j0 = 0; j0 < NPIX; j0 += 64) {
        // ---- scores: 4 j-subtiles of 16, K = 64 (two mfma each) ----
        f32x4 s[4];
        #pragma unroll
        for (int jn = 0; jn < 4; ++jn) {
            const short* grow = Gb + (size_t)(j0 + jn * 16 + l16) * CCH + 8 * lg;
            const short8 gb0 = *(const short8*)(grow);
            const short8 gb1 = *(const short8*)(grow + 32);
            f32x4 acc = (f32x4){0.f, 0.f, 0.f, 0.f};
            acc = __builtin_amdgcn_mfma_f32_16x16x32_bf16(qa0, gb0, acc, 0, 0, 0);
            acc = __builtin_amdgcn_mfma_f32_16x16x32_bf16(qa1, gb1, acc, 0, 0, 0);
            s[jn] = acc;
        }

        // ---- online softmax ----
        float rescale[4];
        #pragma unroll
        for (int r = 0; r < 4; ++r) {
            float mx = fmaxf(fmaxf(s[0][r], s[1][r]), fmaxf(s[2][r], s[3][r]));
            mx = fmaxf(mx, __shfl_xor(mx, 1));
            mx = fmaxf(mx, __shfl_xor(mx, 2));
            mx = fmaxf(mx, __shfl_xor(mx, 4));
            mx = fmaxf(mx, __shfl_xor(mx, 8));
            const float mn = fmaxf(m[r], mx);
            rescale[r] = __expf(m[r] - mn);
            m[r] = mn;
        }
        float psum[4] = {0.f, 0.f, 0.f, 0.f};
        #pragma unroll
        for (int jn = 0; jn < 4; ++jn) {
            #pragma unroll
            for (int r = 0; r < 4; ++r) {
                const float p = __expf(s[jn][r] - m[r]);
                s[jn][r] = p;
                psum[r] += p;
            }
        }
        #pragma unroll
        for (int r = 0; r < 4; ++r) {
            float ps = psum[r];
            ps += __shfl_xor(ps, 1);
            ps += __shfl_xor(ps, 2);
            ps += __shfl_xor(ps, 4);
            ps += __shfl_xor(ps, 8);
            lsum[r] = lsum[r] * rescale[r] + ps;
        }
        #pragma unroll
        for (int nc = 0; nc < 4; ++nc)
            #pragma unroll
            for (int r = 0; r < 4; ++r)
                o[nc][r] *= rescale[r];

        // ---- P -> LDS (bf16), wave-private buffer, no barrier needed ----
        #pragma unroll
        for (int jn = 0; jn < 4; ++jn)
            #pragma unroll
            for (int r = 0; r < 4; ++r)
                Plds[wave][lg * 4 + r][jn * 16 + l16] = __float2bfloat16(s[jn][r]);

        // ---- PV: A-frags from LDS, B-frags from K (contiguous in j) ----
        const short* prow = (const short*)&Plds[wave][l16][0] + 8 * lg;
        const short8 pa0 = *(const short8*)(prow);
        const short8 pa1 = *(const short8*)(prow + 32);
        #pragma unroll
        for (int nc = 0; nc < 4; ++nc) {
            const short* krow = Kb + (size_t)(nc * 16 + l16) * NPIX + j0 + 8 * lg;
            const short8 kb0 = *(const short8*)(krow);
            const short8 kb1 = *(const short8*)(krow + 32);
            o[nc] = __builtin_amdgcn_mfma_f32_16x16x32_bf16(pa0, kb0, o[nc], 0, 0, 0);
            o[nc] = __builtin_amdgcn_mfma_f32_16x16x32_bf16(pa1, kb1, o[nc], 0, 0, 0);
        }
    }

    // ---- epilogue: divide, stage to LDS, coalesced  out = o + x ----
    __shared__ float outs[64][66];            // [c][i_local within block]
    #pragma unroll
    for (int nc = 0; nc < 4; ++nc) {
        #pragma unroll
        for (int r = 0; r < 4; ++r) {
            const int il = wave * 16 + lg * 4 + r;   // i within block tile
            const int c  = nc * 16 + l16;
            outs[c][il] = o[nc][r] / lsum[r];
        }
    }
    __syncthreads();
    for (int e = threadIdx.x; e < 4096; e += 256) {
        const int c = e >> 6, il = e & 63;
        const size_t idx = (size_t)b * CCH * NPIX + (size_t)c * NPIX + i0b + il;
        out[idx] = outs[c][il] + x[idx];
    }
}

extern "C" void kernel_launch(void* const* d_in, const int* in_sizes, int n_in,
                              void* d_out, int out_size, void* d_ws, size_t ws_size,
                              hipStream_t stream) {
    const float* x  = (const float*)d_in[0];
    const float* W1 = (const float*)d_in[1];
    const float* b1 = (const float*)d_in[2];
    const float* W2 = (const float*)d_in[3];
    const float* b2 = (const float*)d_in[4];
    const float* W3 = (const float*)d_in[5];
    const float* b3 = (const float*)d_in[6];
    float* out = (float*)d_out;

    char* ws = (char*)d_ws;
    const size_t planeB = (size_t)NB * NPIX * CCH * sizeof(__hip_bfloat16); // 4 MB
    __hip_bfloat16* Q = (__hip_bfloat16*)(ws);
    __hip_bfloat16* G = (__hip_bfloat16*)(ws + planeB);
    __hip_bfloat16* K = (__hip_bfloat16*)(ws + 2 * planeB);

    proj_kernel<<<dim3(NB * 64), dim3(256), 0, stream>>>(x, W1, b1, W2, b2, W3, b3, Q, G, K);
    attn_kernel<<<dim3(NB * 64), dim3(256), 0, stream>>>(Q, G, K, x, out);
}